// Round 1
// baseline (45.271 us; speedup 1.0000x reference)
//
#include <hip/hip_runtime.h>

#define BB 2
#define NN 256
#define MM 512
#define INF_ 256
#define OUTF 128
#define NEG_INF -1.0e12f

// K1: H = X@W, plus h0 = H.a0, h1 = H.a1, cH = leaky(h0+h1)
// one block per (b,n) row, 128 threads (one per output feature)
__global__ __launch_bounds__(128) void k_gemm(const float* __restrict__ X,
                                              const float* __restrict__ W,
                                              const float* __restrict__ avec,
                                              float* __restrict__ H,
                                              float* __restrict__ h0,
                                              float* __restrict__ h1,
                                              float* __restrict__ cH) {
    int bn = blockIdx.x;      // b*N + n
    int f = threadIdx.x;      // 0..127
    __shared__ float xs[INF_];
    const float* xr = X + bn * INF_;
    xs[f] = xr[f];
    xs[f + 128] = xr[f + 128];
    __syncthreads();
    float acc = 0.f;
#pragma unroll 8
    for (int k = 0; k < INF_; ++k) acc += xs[k] * W[k * OUTF + f];
    H[bn * OUTF + f] = acc;
    float p0 = acc * avec[f];
    float p1 = acc * avec[OUTF + f];
#pragma unroll
    for (int off = 32; off >= 1; off >>= 1) {
        p0 += __shfl_down(p0, off);
        p1 += __shfl_down(p1, off);
    }
    __shared__ float r0[2], r1[2];
    int wave = f >> 6, lane = f & 63;
    if (lane == 0) { r0[wave] = p0; r1[wave] = p1; }
    __syncthreads();
    if (f == 0) {
        float s0 = r0[0] + r0[1];
        float s1 = r1[0] + r1[1];
        h0[bn] = s0;
        h1[bn] = s1;
        float hA = s0 + s1;
        cH[bn] = hA > 0.f ? hA : 0.01f * hA;   // leaky_relu, slope 0.01
    }
}

// K2: deg[b,m] = sum_n A; emA_s[b,m] = sum_n A*h_s / deg;
//     eLow[b,m] = leaky(emA0[(2m)%M] + emA1[(2m+1)%M])
// one block per b, 512 threads (one per m)
__global__ __launch_bounds__(512) void k_em(const float* __restrict__ A,
                                            const float* __restrict__ h0,
                                            const float* __restrict__ h1,
                                            float* __restrict__ eLow) {
    int b = blockIdx.x;
    int m = threadIdx.x;
    __shared__ float sh0[NN], sh1[NN];
    if (m < NN) { sh0[m] = h0[b * NN + m]; sh1[m] = h1[b * NN + m]; }
    __syncthreads();
    const float* Ab = A + b * NN * MM + m;
    float d = 0.f, s0 = 0.f, s1 = 0.f;
#pragma unroll 8
    for (int n = 0; n < NN; ++n) {
        float av = Ab[n * MM];   // coalesced across threads
        d += av;
        s0 += av * sh0[n];
        s1 += av * sh1[n];
    }
    if (d == 0.f) d = 1.f;
    __shared__ float e0[MM], e1[MM];
    e0[m] = s0 / d;
    e1[m] = s1 / d;
    __syncthreads();
    float v = e0[(2 * m) & (MM - 1)] + e1[(2 * m + 1) & (MM - 1)];
    eLow[b * MM + m] = v > 0.f ? v : 0.01f * v;
}

// K3: masked row softmax -> att[b,n,m]
// one block per (b,n), 512 threads (one per m)
__global__ __launch_bounds__(512) void k_att(const float* __restrict__ A,
                                             const float* __restrict__ cH,
                                             const float* __restrict__ eLow,
                                             float* __restrict__ att) {
    int bn = blockIdx.x;
    int b = bn >> 8, n = bn & 255;
    int m = threadIdx.x;
    float av = A[bn * MM + m];
    float ev = (n < 128) ? cH[b * NN + 2 * n + (m >= 256 ? 1 : 0)]
                         : eLow[b * MM + m];
    float masked = av > 0.f ? ev : NEG_INF;
    float mx = masked;
#pragma unroll
    for (int off = 32; off >= 1; off >>= 1) mx = fmaxf(mx, __shfl_xor(mx, off));
    __shared__ float wmx[8];
    int wave = m >> 6, lane = m & 63;
    if (lane == 0) wmx[wave] = mx;
    __syncthreads();
    float bmx = wmx[0];
#pragma unroll
    for (int i = 1; i < 8; ++i) bmx = fmaxf(bmx, wmx[i]);
    float ex = expf(masked - bmx);
    float s = ex;
#pragma unroll
    for (int off = 32; off >= 1; off >>= 1) s += __shfl_xor(s, off);
    __shared__ float wsm[8];
    if (lane == 0) wsm[wave] = s;
    __syncthreads();
    float bs = 0.f;
#pragma unroll
    for (int i = 0; i < 8; ++i) bs += wsm[i];
    att[bn * MM + m] = ex / bs;
}

// K4: h'[b,m,f] = sum_n att[b,n,m] * H[b,n,f]
// 256 blocks x 512 threads: block = (b, group of 4 m), thread = (m_local, f)
__global__ __launch_bounds__(512) void k_out(const float* __restrict__ att,
                                             const float* __restrict__ H,
                                             float* __restrict__ out) {
    int blk = blockIdx.x;
    int b = blk >> 7, mg = blk & 127;
    int m = mg * 4 + (threadIdx.x >> 7);
    int f = threadIdx.x & 127;
    const float* ap = att + b * NN * MM + m;
    const float* hp = H + b * NN * OUTF + f;
    float acc = 0.f;
#pragma unroll 4
    for (int n = 0; n < NN; ++n) acc += ap[n * MM] * hp[n * OUTF];
    out[(b * MM + m) * OUTF + f] = acc;
}

extern "C" void kernel_launch(void* const* d_in, const int* in_sizes, int n_in,
                              void* d_out, int out_size, void* d_ws, size_t ws_size,
                              hipStream_t stream) {
    const float* X = (const float*)d_in[0];
    const float* A = (const float*)d_in[1];
    const float* W = (const float*)d_in[2];
    const float* a = (const float*)d_in[3];
    float* out = (float*)d_out;
    float* ws = (float*)d_ws;

    float* H    = ws;            // B*N*OUTF = 65536
    float* h0   = ws + 65536;    // 512
    float* h1   = ws + 66048;    // 512
    float* cH   = ws + 66560;    // 512
    float* eLow = ws + 67072;    // B*M = 1024
    float* att  = ws + 68096;    // B*N*M = 262144

    k_gemm<<<BB * NN, 128, 0, stream>>>(X, W, a, H, h0, h1, cH);
    k_em<<<BB, 512, 0, stream>>>(A, h0, h1, eLow);
    k_att<<<BB * NN, 512, 0, stream>>>(A, cH, eLow, att);
    k_out<<<256, 512, 0, stream>>>(att, H, out);
}

// Round 2
// 39.122 us; speedup vs baseline: 1.1572x; 1.1572x over previous
//
#include <hip/hip_runtime.h>

#define BB 2
#define NN 256
#define MM 512
#define INF_ 256
#define OUTF 128
#define NEG_INF -1.0e12f

// K1: H = X@W, plus h0 = H.a0, h1 = H.a1, cH = leaky(h0+h1)
// one block per (b,n) row, 256 threads: f = t&127, k-half = t>>7 (split-K)
__global__ __launch_bounds__(256) void k_gemm(const float* __restrict__ X,
                                              const float* __restrict__ W,
                                              const float* __restrict__ avec,
                                              float* __restrict__ H,
                                              float* __restrict__ h0,
                                              float* __restrict__ h1,
                                              float* __restrict__ cH) {
    int bn = blockIdx.x;      // b*N + n
    int t = threadIdx.x;
    int f = t & 127, kh = t >> 7;
    __shared__ float xs[INF_];
    xs[t] = X[bn * INF_ + t];
    __syncthreads();
    float acc = 0.f;
    const float* Wp = W + kh * 128 * OUTF + f;
    const float* xp = xs + kh * 128;
#pragma unroll 8
    for (int k = 0; k < 128; ++k) acc += xp[k] * Wp[k * OUTF];
    __shared__ float accs[256];
    accs[t] = acc;
    __syncthreads();
    // combine the two K-halves; threads 0..127 own feature f=t
    float a2 = 0.f;
    if (t < 128) {
        a2 = accs[t] + accs[t + 128];
        H[bn * OUTF + t] = a2;
    }
    float p0 = (t < 128) ? a2 * avec[t] : 0.f;
    float p1 = (t < 128) ? a2 * avec[OUTF + t] : 0.f;
#pragma unroll
    for (int off = 32; off >= 1; off >>= 1) {
        p0 += __shfl_down(p0, off);
        p1 += __shfl_down(p1, off);
    }
    __shared__ float r0[4], r1[4];
    int wv = t >> 6, ln = t & 63;
    if (ln == 0) { r0[wv] = p0; r1[wv] = p1; }
    __syncthreads();
    if (t == 0) {
        float s0 = r0[0] + r0[1] + r0[2] + r0[3];
        float s1 = r1[0] + r1[1] + r1[2] + r1[3];
        h0[bn] = s0;
        h1[bn] = s1;
        float hA = s0 + s1;
        cH[bn] = hA > 0.f ? hA : 0.01f * hA;   // leaky_relu, slope 0.01
    }
}

// K2: emA0[b,m] = (sum_n A*h0)/deg ; emA1 likewise (deg 0 -> 1)
// 32 blocks: b = blk>>4, m-quad mq = blk&15 (32 m each).
// 256 threads: m_l = t&31, n_l = t>>5 (8-way split of the n-reduction).
__global__ __launch_bounds__(256) void k_em(const float* __restrict__ A,
                                            const float* __restrict__ h0,
                                            const float* __restrict__ h1,
                                            float* __restrict__ emA0,
                                            float* __restrict__ emA1) {
    int blk = blockIdx.x;
    int b = blk >> 4, mq = blk & 15;
    int t = threadIdx.x;
    int m_l = t & 31, n_l = t >> 5;
    int m = mq * 32 + m_l;
    __shared__ float sh0[NN], sh1[NN];
    sh0[t] = h0[b * NN + t];
    sh1[t] = h1[b * NN + t];
    __syncthreads();
    const float* Ap = A + (size_t)b * NN * MM + m;
    float d = 0.f, s0 = 0.f, s1 = 0.f;
#pragma unroll 8
    for (int i = 0; i < 32; ++i) {
        int n = n_l * 32 + i;
        float av = Ap[n * MM];   // coalesced across m_l lanes
        d += av;
        s0 += av * sh0[n];
        s1 += av * sh1[n];
    }
    __shared__ float sd[256], ss0[256], ss1[256];
    sd[t] = d; ss0[t] = s0; ss1[t] = s1;
    __syncthreads();
    if (t < 32) {
        float D = 0.f, S0 = 0.f, S1 = 0.f;
#pragma unroll
        for (int j = 0; j < 8; ++j) {
            D += sd[j * 32 + t];
            S0 += ss0[j * 32 + t];
            S1 += ss1[j * 32 + t];
        }
        if (D == 0.f) D = 1.f;
        emA0[b * MM + mq * 32 + t] = S0 / D;
        emA1[b * MM + mq * 32 + t] = S1 / D;
    }
}

// K3: masked row softmax -> att[b,n,m]; eLow computed inline from emA
// one block per (b,n), 512 threads (one per m)
__global__ __launch_bounds__(512) void k_att(const float* __restrict__ A,
                                             const float* __restrict__ cH,
                                             const float* __restrict__ emA0,
                                             const float* __restrict__ emA1,
                                             float* __restrict__ att) {
    int bn = blockIdx.x;
    int b = bn >> 8, n = bn & 255;
    int m = threadIdx.x;
    float av = A[(size_t)bn * MM + m];
    float ev;
    if (n < 128) {
        ev = cH[b * NN + 2 * n + (m >= 256 ? 1 : 0)];
    } else {
        float v = emA0[b * MM + ((2 * m) & (MM - 1))] +
                  emA1[b * MM + ((2 * m + 1) & (MM - 1))];
        ev = v > 0.f ? v : 0.01f * v;
    }
    float masked = av > 0.f ? ev : NEG_INF;
    float mx = masked;
#pragma unroll
    for (int off = 32; off >= 1; off >>= 1) mx = fmaxf(mx, __shfl_xor(mx, off));
    __shared__ float wmx[8];
    int wave = m >> 6, lane = m & 63;
    if (lane == 0) wmx[wave] = mx;
    __syncthreads();
    float bmx = wmx[0];
#pragma unroll
    for (int i = 1; i < 8; ++i) bmx = fmaxf(bmx, wmx[i]);
    float ex = expf(masked - bmx);
    float s = ex;
#pragma unroll
    for (int off = 32; off >= 1; off >>= 1) s += __shfl_xor(s, off);
    __shared__ float wsm[8];
    if (lane == 0) wsm[wave] = s;
    __syncthreads();
    float bs = 0.f;
#pragma unroll
    for (int i = 0; i < 8; ++i) bs += wsm[i];
    att[(size_t)bn * MM + m] = ex / bs;
}

// K4: h'[b,m,f] = sum_n att[b,n,m] * H[b,n,f]
// 256 blocks x 512 threads: block = (b, group of 4 m), thread = (m_local, f)
__global__ __launch_bounds__(512) void k_out(const float* __restrict__ att,
                                             const float* __restrict__ H,
                                             float* __restrict__ out) {
    int blk = blockIdx.x;
    int b = blk >> 7, mg = blk & 127;
    int m = mg * 4 + (threadIdx.x >> 7);
    int f = threadIdx.x & 127;
    const float* ap = att + (size_t)b * NN * MM + m;
    const float* hp = H + (size_t)b * NN * OUTF + f;
    float acc = 0.f;
#pragma unroll 4
    for (int n = 0; n < NN; ++n) acc += ap[n * MM] * hp[n * OUTF];
    out[((size_t)b * MM + m) * OUTF + f] = acc;
}

extern "C" void kernel_launch(void* const* d_in, const int* in_sizes, int n_in,
                              void* d_out, int out_size, void* d_ws, size_t ws_size,
                              hipStream_t stream) {
    const float* X = (const float*)d_in[0];
    const float* A = (const float*)d_in[1];
    const float* W = (const float*)d_in[2];
    const float* a = (const float*)d_in[3];
    float* out = (float*)d_out;
    float* ws = (float*)d_ws;

    float* H    = ws;            // B*N*OUTF = 65536
    float* h0   = ws + 65536;    // 512
    float* h1   = ws + 66048;    // 512
    float* cH   = ws + 66560;    // 512
    float* emA0 = ws + 67072;    // B*M = 1024
    float* emA1 = ws + 68096;    // B*M = 1024
    float* att  = ws + 69120;    // B*N*M = 262144

    k_gemm<<<BB * NN, 256, 0, stream>>>(X, W, a, H, h0, h1, cH);
    k_em<<<32, 256, 0, stream>>>(A, h0, h1, emA0, emA1);
    k_att<<<BB * NN, 512, 0, stream>>>(A, cH, emA0, emA1, att);
    k_out<<<256, 512, 0, stream>>>(att, H, out);
}